// Round 1
// baseline (115.861 us; speedup 1.0000x reference)
//
#include <hip/hip_runtime.h>
#include <math.h>

#define BLK 256
#define G 8
#define MODES_PER_BLK 800   /* 6400 / G */
#define MDIM 80

__device__ __forceinline__ double softplus_d(double x) {
    return (x > 30.0) ? x : log1p(exp(x));
}

__global__ void zero_out_kernel(float* __restrict__ out, int N) {
    int i = blockIdx.x * blockDim.x + threadIdx.x;
    if (i < N) out[i] = 0.0f;
}

__global__ __launch_bounds__(BLK) void modal_main_kernel(
    const float* __restrict__ mu_raw_p, const float* __restrict__ Dmu_raw_p,
    const float* __restrict__ T0mu_raw_p, const float* __restrict__ Ly_raw_p,
    const float* __restrict__ xo_raw_p, const float* __restrict__ yo_raw_p,
    float* __restrict__ out, int N)
{
    __shared__ float4 md[MODES_PER_BLK];
    __shared__ int cnt;
    if (threadIdx.x == 0) cnt = 0;
    __syncthreads();

    const double PI_D     = 3.14159265358979323846;
    const double TWO_PI_D = 6.28318530717958647693;
    const double INV2PI_D = 0.15915494309189533577;
    const double LX = 0.5;
    const double Kd = 1.0 / 44100.0;
    const double MAX_OM = 10000.0 * TWO_PI_D;
    const double MIN_OM = 20.0 * TWO_PI_D;

    // float32-rounded constants, exactly as the reference bakes them
    const double OM2   = TWO_PI_D * 500.0;
    const double DOMSQ = OM2 * OM2;
    const float ALPHA_F = (float)(3.0 * log(10.0) / DOMSQ * (OM2 * OM2 / 6.0));
    const float BETA_F  = (float)(3.0 * log(10.0) / DOMSQ * (1.0 / 1.0 - 1.0 / 6.0));

    // scalar input transforms (every thread; trivial cost)
    const double mu   = softplus_d((double)mu_raw_p[0])  + 1e-4;
    const double Dmu  = softplus_d((double)Dmu_raw_p[0]) + 1e-4;
    const double T0mu = softplus_d((double)T0mu_raw_p[0]) + 1e-4;
    const double Ly   = 1.1 + (4.0 - 1.1) * ((tanh((double)Ly_raw_p[0]) + 1.0) * 0.5);
    const double xo   = 0.49 * LX + (1.0 - 0.49) * LX * ((tanh((double)xo_raw_p[0]) + 1.0) * 0.5);
    const double yo   = 0.51 * Ly + (1.0 - 0.51) * Ly * ((tanh((double)yo_raw_p[0]) + 1.0) * 0.5);
    const double xi = 0.1 * LX;
    const double yi = 0.1 * Ly;
    const double ms = 0.25 * mu * LX * Ly;

    const int n0 = blockIdx.x * BLK;
    const int gy = blockIdx.y;

    // per-block mode setup: strided 1/G of the 6400 raw modes, compacted into LDS
    for (int j = threadIdx.x; j < MODES_PER_BLK; j += BLK) {
        const int r = gy + G * j;                 // raw mode index in [0, 6400)
        const double mm = (double)(r / MDIM + 1); // M_VEC
        const double nn = (double)(r % MDIM + 1); // N_VEC
        const double a1 = mm * PI_D / LX;
        const double a2 = nn * PI_D / Ly;
        const double g1 = a1 * a1 + a2 * a2;
        double osq = T0mu * g1 + Dmu * g1 * g1;
        if (osq < 0.0) osq = 0.0;
        const double omega = sqrt(osq);
        if (!(omega >= MIN_OM && omega <= MAX_OM)) continue;   // valid mask

        const double w   = omega * Kd;
        const double sig = (double)ALPHA_F + (double)BETA_F * (omega * omega);
        const double in_w  = cos(xi * a1) * cos(yi * a2);
        const double out_w = cos(xo * a1) * cos(yo * a2);
        const double denom = sin(w) + 1e-8;
        // P/denom with exp(-sig*K) folded: term_n = A * exp(-sig*K*n) * sin(n*w)
        const double Afull = out_w * in_w * (Kd * Kd) / ms / denom;
        // fold block-base decay into amplitude; prunes dead modes for late tiles
        const double Ablk = Afull * exp(-sig * Kd * (double)n0);
        if (fabs(Ablk) < 1e-20) continue;

        // per-block phase base: (n0 * w) mod 2pi, computed in f64
        const double ph0 = (double)n0 * w;
        const double qd  = rint(ph0 * INV2PI_D);
        const float base = (float)(ph0 - qd * TWO_PI_D);

        const int s = atomicAdd(&cnt, 1);
        md[s] = make_float4(base, (float)w, (float)(sig * Kd), (float)Ablk);
    }
    __syncthreads();

    const int count = cnt;
    const int t = threadIdx.x;
    const int n = n0 + t;
    if (n < N) {
        const float tf = (float)t;
        const float INV2PI_F = 0.15915494f;
        const float P2H = 6.2831855f;        // (float)2pi
        const float P2L = -1.7484555e-7f;    // 2pi - (float)2pi
        float acc = 0.0f;
        for (int j = 0; j < count; ++j) {
            const float4 v = md[j];          // broadcast LDS read (conflict-free)
            const float ph = fmaf(tf, v.y, v.x);          // |ph| <= ~364
            const float q  = rintf(ph * INV2PI_F);
            float red = fmaf(-q, P2H, ph);
            red       = fmaf(-q, P2L, red);               // |red| <= pi
            const float s = __sinf(red);
            const float e = __expf(-v.z * tf);            // arg in [-13.4, 0]
            acc = fmaf(v.w * e, s, acc);
        }
        atomicAdd(&out[n], acc);
    }
}

__global__ __launch_bounds__(1024) void reduce_max_kernel(
    const float* __restrict__ disp, int N, float* __restrict__ ws)
{
    float m = 0.0f;
    for (int i = threadIdx.x; i < N; i += 1024) m = fmaxf(m, fabsf(disp[i]));
    #pragma unroll
    for (int o = 32; o > 0; o >>= 1) m = fmaxf(m, __shfl_down(m, o));
    __shared__ float sm[16];
    const int wid = threadIdx.x >> 6;
    const int lane = threadIdx.x & 63;
    if (lane == 0) sm[wid] = m;
    __syncthreads();
    if (threadIdx.x == 0) {
        float mm = sm[0];
        #pragma unroll
        for (int i = 1; i < 16; ++i) mm = fmaxf(mm, sm[i]);
        ws[0] = 1.0f / (mm + 1e-8f);   // peak = max|disp| + 1e-8
    }
}

__global__ void scale_kernel(float* __restrict__ out, int N, const float* __restrict__ ws) {
    int i = blockIdx.x * blockDim.x + threadIdx.x;
    const float inv = ws[0];
    if (i < N) out[i] *= inv;
}

extern "C" void kernel_launch(void* const* d_in, const int* in_sizes, int n_in,
                              void* d_out, int out_size, void* d_ws, size_t ws_size,
                              hipStream_t stream) {
    const float* mu_raw   = (const float*)d_in[0];
    const float* Dmu_raw  = (const float*)d_in[1];
    const float* T0mu_raw = (const float*)d_in[2];
    const float* Ly_raw   = (const float*)d_in[3];
    const float* xo_raw   = (const float*)d_in[4];
    const float* yo_raw   = (const float*)d_in[5];
    // d_in[6] = num_samples; equals out_size, which is host-visible — use that.
    float* out = (float*)d_out;
    float* ws  = (float*)d_ws;
    const int N = out_size;
    const int nb = (N + BLK - 1) / BLK;

    zero_out_kernel<<<nb, BLK, 0, stream>>>(out, N);
    dim3 grid(nb, G);
    modal_main_kernel<<<grid, BLK, 0, stream>>>(mu_raw, Dmu_raw, T0mu_raw,
                                                Ly_raw, xo_raw, yo_raw, out, N);
    reduce_max_kernel<<<1, 1024, 0, stream>>>(out, N, ws);
    scale_kernel<<<nb, BLK, 0, stream>>>(out, N, ws);
}

// Round 2
// 96.849 us; speedup vs baseline: 1.1963x; 1.1963x over previous
//
#include <hip/hip_runtime.h>
#include <math.h>

#define BLK 256
#define G 16
#define NMODES 6400
#define STRIPE (NMODES / G)   /* 400 */
#define MDIM 80

// Persistent device-global scratch (not touched by the harness's 0xAA poison;
// fully rewritten every call, so every launch does identical work).
__device__ float4   g_records[NMODES];
__device__ unsigned g_maxbits;

// Raw gfx950 transcendentals. v_sin_f32: D = sin(S0 * 2pi) (input in
// revolutions, pre-reduced with v_fract). v_exp_f32: D = 2^S0.
__device__ __forceinline__ float v_fract(float x){ float r; asm("v_fract_f32 %0, %1" : "=v"(r) : "v"(x)); return r; }
__device__ __forceinline__ float v_sin_rev(float x){ float r; asm("v_sin_f32 %0, %1" : "=v"(r) : "v"(x)); return r; }
__device__ __forceinline__ float v_exp2(float x){ float r; asm("v_exp_f32 %0, %1" : "=v"(r) : "v"(x)); return r; }

__device__ __forceinline__ double softplus_d(double x) {
    return (x > 30.0) ? x : log1p(exp(x));
}

// Dispatch 1: zero the output, reset the max slot, and derive all 6400 mode
// records ONCE (f64 math). Record: {w_rev_hi, w_rev_lo, -sigma*K*log2(e), A},
// A == 0 marks invalid.
__global__ __launch_bounds__(BLK) void setup_zero_kernel(
    const float* __restrict__ mu_raw_p, const float* __restrict__ Dmu_raw_p,
    const float* __restrict__ T0mu_raw_p, const float* __restrict__ Ly_raw_p,
    const float* __restrict__ xo_raw_p, const float* __restrict__ yo_raw_p,
    float* __restrict__ out, int N)
{
    const int gid = blockIdx.x * BLK + threadIdx.x;
    if (gid < N) out[gid] = 0.0f;
    if (gid == 0) g_maxbits = 0u;
    if (gid >= NMODES) return;

    const double PI_D     = 3.14159265358979323846;
    const double TWO_PI_D = 6.28318530717958647693;
    const double INV2PI_D = 0.15915494309189533577;
    const double LOG2E_D  = 1.44269504088896340736;
    const double LX = 0.5;
    const double Kd = 1.0 / 44100.0;
    const double MAX_OM = 10000.0 * TWO_PI_D;
    const double MIN_OM = 20.0 * TWO_PI_D;

    // float32-rounded constants, exactly as the reference bakes them
    const double OM2   = TWO_PI_D * 500.0;
    const double DOMSQ = OM2 * OM2;
    const float ALPHA_F = (float)(3.0 * log(10.0) / DOMSQ * (OM2 * OM2 / 6.0));
    const float BETA_F  = (float)(3.0 * log(10.0) / DOMSQ * (1.0 / 1.0 - 1.0 / 6.0));

    const double mu   = softplus_d((double)mu_raw_p[0])  + 1e-4;
    const double Dmu  = softplus_d((double)Dmu_raw_p[0]) + 1e-4;
    const double T0mu = softplus_d((double)T0mu_raw_p[0]) + 1e-4;
    const double Ly   = 1.1 + (4.0 - 1.1) * ((tanh((double)Ly_raw_p[0]) + 1.0) * 0.5);
    const double xo   = 0.49 * LX + (1.0 - 0.49) * LX * ((tanh((double)xo_raw_p[0]) + 1.0) * 0.5);
    const double yo   = 0.51 * Ly + (1.0 - 0.51) * Ly * ((tanh((double)yo_raw_p[0]) + 1.0) * 0.5);
    const double xi = 0.1 * LX;
    const double yi = 0.1 * Ly;
    const double ms = 0.25 * mu * LX * Ly;

    const double mm = (double)(gid / MDIM + 1);   // M_VEC
    const double nn = (double)(gid % MDIM + 1);   // N_VEC
    const double a1 = mm * PI_D / LX;
    const double a2 = nn * PI_D / Ly;
    const double g1 = a1 * a1 + a2 * a2;
    double osq = T0mu * g1 + Dmu * g1 * g1;
    if (osq < 0.0) osq = 0.0;
    const double omega = sqrt(osq);

    float4 rec = make_float4(0.0f, 0.0f, 0.0f, 0.0f);
    if (omega >= MIN_OM && omega <= MAX_OM) {
        const double w     = omega * Kd;
        const double sig   = (double)ALPHA_F + (double)BETA_F * (omega * omega);
        const double in_w  = cos(xi * a1) * cos(yi * a2);
        const double out_w = cos(xo * a1) * cos(yo * a2);
        const double denom = sin(w) + 1e-8;
        // term_n = A * exp(-sig*K*n) * sin(n*w)   (exp(-sig*K) of the
        // reference's P folds with decay_env's (n-1) to give exponent n)
        const double A = out_w * in_w * (Kd * Kd) / ms / denom;
        const double wrev = w * INV2PI_D;
        const float hi = (float)wrev;
        const float lo = (float)(wrev - (double)hi);
        rec = make_float4(hi, lo, (float)(-sig * Kd * LOG2E_D), (float)A);
    }
    g_records[gid] = rec;
}

// Dispatch 2: grid (ceil(N/256), G). Block (bx, gy) computes samples
// [bx*256, bx*256+256) over mode stripe {gy + G*j}. Cheap per-block fold
// compacts alive modes into LDS, then a 7-instruction inner loop.
__global__ __launch_bounds__(BLK, 8) void modal_main_kernel(
    float* __restrict__ out, int N)
{
    __shared__ float4 md[STRIPE];
    __shared__ int cnt;
    if (threadIdx.x == 0) cnt = 0;
    __syncthreads();

    const int n0  = blockIdx.x * BLK;
    const int gy  = blockIdx.y;
    const float n0f = (float)n0;

    for (int j = threadIdx.x; j < STRIPE; j += BLK) {
        const float4 rec = g_records[gy + G * j];
        if (rec.w == 0.0f) continue;                       // invalid mode
        const float ampf = rec.w * v_exp2(rec.z * n0f);    // fold block-base decay
        if (fabsf(ampf) < 1e-18f) continue;                // fully decayed
        const double wrev = (double)rec.x + (double)rec.y;
        const double p0   = (double)n0 * wrev;
        const float base  = (float)(p0 - rint(p0));        // phase base, revolutions
        const int s = atomicAdd(&cnt, 1);
        md[s] = make_float4(base, rec.x, rec.z, ampf);
    }
    __syncthreads();

    const int count = cnt;
    const int n = n0 + threadIdx.x;
    if (n < N) {
        const float tf = (float)threadIdx.x;
        float acc = 0.0f;
        for (int j = 0; j < count; ++j) {
            const float4 v = md[j];                 // broadcast LDS read
            const float rev = fmaf(tf, v.y, v.x);   // phase in revolutions
            const float s   = v_sin_rev(v_fract(rev));
            const float e   = v_exp2(v.z * tf);
            acc = fmaf(v.w * e, s, acc);
        }
        atomicAdd(&out[n], acc);
    }
}

// Dispatch 3: per-block max -> uint atomicMax (valid: all values >= 0).
__global__ __launch_bounds__(BLK) void block_max_kernel(
    const float* __restrict__ out, int N)
{
    const int i = blockIdx.x * BLK + threadIdx.x;
    float m = (i < N) ? fabsf(out[i]) : 0.0f;
    #pragma unroll
    for (int o = 32; o > 0; o >>= 1) m = fmaxf(m, __shfl_down(m, o));
    __shared__ float sm[4];
    const int w = threadIdx.x >> 6, l = threadIdx.x & 63;
    if (l == 0) sm[w] = m;
    __syncthreads();
    if (threadIdx.x == 0) {
        const float mm = fmaxf(fmaxf(sm[0], sm[1]), fmaxf(sm[2], sm[3]));
        atomicMax(&g_maxbits, __float_as_uint(mm));
    }
}

// Dispatch 4: normalize.
__global__ __launch_bounds__(BLK) void scale_kernel(float* __restrict__ out, int N)
{
    const int i = blockIdx.x * BLK + threadIdx.x;
    const float inv = 1.0f / (__uint_as_float(g_maxbits) + 1e-8f);
    if (i < N) out[i] *= inv;
}

extern "C" void kernel_launch(void* const* d_in, const int* in_sizes, int n_in,
                              void* d_out, int out_size, void* d_ws, size_t ws_size,
                              hipStream_t stream) {
    const float* mu_raw   = (const float*)d_in[0];
    const float* Dmu_raw  = (const float*)d_in[1];
    const float* T0mu_raw = (const float*)d_in[2];
    const float* Ly_raw   = (const float*)d_in[3];
    const float* xo_raw   = (const float*)d_in[4];
    const float* yo_raw   = (const float*)d_in[5];
    float* out = (float*)d_out;
    const int N = out_size;
    int nb = (N + BLK - 1) / BLK;
    const int nb_setup = (NMODES + BLK - 1) / BLK;
    if (nb < nb_setup) nb = nb_setup;   // ensure mode threads exist even for tiny N

    setup_zero_kernel<<<nb, BLK, 0, stream>>>(mu_raw, Dmu_raw, T0mu_raw,
                                              Ly_raw, xo_raw, yo_raw, out, N);
    modal_main_kernel<<<dim3(nb, G), BLK, 0, stream>>>(out, N);
    block_max_kernel<<<nb, BLK, 0, stream>>>(out, N);
    scale_kernel<<<nb, BLK, 0, stream>>>(out, N);
}

// Round 3
// 96.138 us; speedup vs baseline: 1.2052x; 1.0074x over previous
//
#include <hip/hip_runtime.h>
#include <math.h>

#define BLK 256
#define G 16
#define NMODES 6400
#define STRIPE (NMODES / G)   /* 400 */
#define MDIM 80

// Persistent device-global scratch (never touched by the harness's 0xAA
// poison; fully rewritten every call -> identical work per launch).
__device__ float4   g_records[NMODES];
__device__ unsigned g_maxbits;

// Raw gfx950 transcendentals. v_sin_f32: D = sin(S0 * 2pi) (input in
// revolutions, pre-reduced with v_fract). v_exp_f32: D = 2^S0.
__device__ __forceinline__ float v_fract(float x){ float r; asm("v_fract_f32 %0, %1" : "=v"(r) : "v"(x)); return r; }
__device__ __forceinline__ float v_sin_rev(float x){ float r; asm("v_sin_f32 %0, %1" : "=v"(r) : "v"(x)); return r; }
__device__ __forceinline__ float v_exp2(float x){ float r; asm("v_exp_f32 %0, %1" : "=v"(r) : "v"(x)); return r; }

__device__ __forceinline__ double softplus_d(double x) {
    return (x > 30.0) ? x : log1p(exp(x));
}

// Dispatch 1: zero output, reset max slot, derive all 6400 mode records ONCE
// (f64 math). Record: {w_rev_hi, w_rev_lo, -sigma*K*log2(e), A}; A==0 invalid.
__global__ __launch_bounds__(BLK) void setup_zero_kernel(
    const float* __restrict__ mu_raw_p, const float* __restrict__ Dmu_raw_p,
    const float* __restrict__ T0mu_raw_p, const float* __restrict__ Ly_raw_p,
    const float* __restrict__ xo_raw_p, const float* __restrict__ yo_raw_p,
    float* __restrict__ out, int N)
{
    const int gid = blockIdx.x * BLK + threadIdx.x;
    if (gid < N) out[gid] = 0.0f;
    if (gid == 0) g_maxbits = 0u;
    if (gid >= NMODES) return;

    const double PI_D     = 3.14159265358979323846;
    const double TWO_PI_D = 6.28318530717958647693;
    const double INV2PI_D = 0.15915494309189533577;
    const double LOG2E_D  = 1.44269504088896340736;
    const double LX = 0.5;
    const double Kd = 1.0 / 44100.0;
    const double MAX_OM = 10000.0 * TWO_PI_D;
    const double MIN_OM = 20.0 * TWO_PI_D;

    // float32-rounded constants, exactly as the reference bakes them
    const double OM2   = TWO_PI_D * 500.0;
    const double DOMSQ = OM2 * OM2;
    const float ALPHA_F = (float)(3.0 * log(10.0) / DOMSQ * (OM2 * OM2 / 6.0));
    const float BETA_F  = (float)(3.0 * log(10.0) / DOMSQ * (1.0 / 1.0 - 1.0 / 6.0));

    const double mu   = softplus_d((double)mu_raw_p[0])  + 1e-4;
    const double Dmu  = softplus_d((double)Dmu_raw_p[0]) + 1e-4;
    const double T0mu = softplus_d((double)T0mu_raw_p[0]) + 1e-4;
    const double Ly   = 1.1 + (4.0 - 1.1) * ((tanh((double)Ly_raw_p[0]) + 1.0) * 0.5);
    const double xo   = 0.49 * LX + (1.0 - 0.49) * LX * ((tanh((double)xo_raw_p[0]) + 1.0) * 0.5);
    const double yo   = 0.51 * Ly + (1.0 - 0.51) * Ly * ((tanh((double)yo_raw_p[0]) + 1.0) * 0.5);
    const double xi = 0.1 * LX;
    const double yi = 0.1 * Ly;
    const double ms = 0.25 * mu * LX * Ly;

    const double mm = (double)(gid / MDIM + 1);   // M_VEC
    const double nn = (double)(gid % MDIM + 1);   // N_VEC
    const double a1 = mm * PI_D / LX;
    const double a2 = nn * PI_D / Ly;
    const double g1 = a1 * a1 + a2 * a2;
    double osq = T0mu * g1 + Dmu * g1 * g1;
    if (osq < 0.0) osq = 0.0;
    const double omega = sqrt(osq);

    float4 rec = make_float4(0.0f, 0.0f, 0.0f, 0.0f);
    if (omega >= MIN_OM && omega <= MAX_OM) {
        const double w     = omega * Kd;
        const double sig   = (double)ALPHA_F + (double)BETA_F * (omega * omega);
        const double in_w  = cos(xi * a1) * cos(yi * a2);
        const double out_w = cos(xo * a1) * cos(yo * a2);
        const double denom = sin(w) + 1e-8;
        // term_n = A * exp(-sig*K*n) * sin(n*w)
        const double A = out_w * in_w * (Kd * Kd) / ms / denom;
        const double wrev = w * INV2PI_D;
        const float hi = (float)wrev;
        const float lo = (float)(wrev - (double)hi);
        rec = make_float4(hi, lo, (float)(-sig * Kd * LOG2E_D), (float)A);
    }
    g_records[gid] = rec;
}

// Dispatch 2: grid (ceil(N/256), G). Block (bx, gy) computes samples
// [bx*256, bx*256+256) over mode stripe {gy + G*j}. Wave-aggregated
// compaction of alive modes into LDS, then a tight f32 inner loop.
__global__ __launch_bounds__(BLK, 8) void modal_main_kernel(
    float* __restrict__ out, int N)
{
    __shared__ float4 md[STRIPE];
    __shared__ int cnt;
    if (threadIdx.x == 0) cnt = 0;
    __syncthreads();

    const int n0  = blockIdx.x * BLK;
    const int gy  = blockIdx.y;
    const float n0f = (float)n0;
    const int lane = threadIdx.x & 63;

    for (int j0 = 0; j0 < STRIPE; j0 += BLK) {
        const int j = j0 + threadIdx.x;
        bool alive = false;
        float4 orec;
        if (j < STRIPE) {
            const float4 rec = g_records[gy + G * j];
            if (rec.w != 0.0f) {
                const float ampf = rec.w * v_exp2(rec.z * n0f);  // fold decay
                if (fabsf(ampf) >= 1e-18f) {
                    const double wrev = (double)rec.x + (double)rec.y;
                    const double p0   = (double)n0 * wrev;
                    const float base  = (float)(p0 - rint(p0));  // phase base (revs)
                    orec = make_float4(base, rec.x, rec.z, ampf);
                    alive = true;
                }
            }
        }
        // one LDS atomic per wave instead of one per alive lane
        const unsigned long long mask = __ballot(alive);
        const int nw = __popcll(mask);
        int base_slot = 0;
        if (lane == 0 && nw) base_slot = atomicAdd(&cnt, nw);
        base_slot = __shfl(base_slot, 0, 64);
        if (alive) {
            const int s = base_slot + __popcll(mask & ((1ull << lane) - 1ull));
            md[s] = orec;
        }
    }
    __syncthreads();

    const int count = cnt;
    if (count == 0) return;            // fully-decayed stripe: skip atomics
    const int n = n0 + threadIdx.x;
    if (n >= N) return;

    const float tf = (float)threadIdx.x;
    float acc = 0.0f;
    for (int j = 0; j < count; ++j) {
        const float4 v = md[j];                 // broadcast LDS read
        const float rev = fmaf(tf, v.y, v.x);   // phase in revolutions
        const float s   = v_sin_rev(v_fract(rev));
        const float e   = v_exp2(v.z * tf);
        acc = fmaf(v.w * e, s, acc);
    }
    if (acc != 0.0f) atomicAdd(&out[n], acc);
}

// Dispatch 3: vectorized per-block max -> uint atomicMax (values >= 0).
__global__ __launch_bounds__(BLK) void block_max_kernel(
    const float* __restrict__ out, int N)
{
    const int nvec = N >> 2;
    const int i = blockIdx.x * BLK + threadIdx.x;
    float m = 0.0f;
    if (i < nvec) {
        const float4 v = ((const float4*)out)[i];
        m = fmaxf(fmaxf(fabsf(v.x), fabsf(v.y)), fmaxf(fabsf(v.z), fabsf(v.w)));
    }
    if (blockIdx.x == 0 && threadIdx.x < (N & 3))
        m = fmaxf(m, fabsf(out[(nvec << 2) + threadIdx.x]));
    #pragma unroll
    for (int o = 32; o > 0; o >>= 1) m = fmaxf(m, __shfl_down(m, o));
    __shared__ float sm[4];
    const int w = threadIdx.x >> 6, l = threadIdx.x & 63;
    if (l == 0) sm[w] = m;
    __syncthreads();
    if (threadIdx.x == 0) {
        const float mm = fmaxf(fmaxf(sm[0], sm[1]), fmaxf(sm[2], sm[3]));
        atomicMax(&g_maxbits, __float_as_uint(mm));
    }
}

// Dispatch 4: normalize (vectorized).
__global__ __launch_bounds__(BLK) void scale_kernel(float* __restrict__ out, int N)
{
    const float inv = 1.0f / (__uint_as_float(g_maxbits) + 1e-8f);
    const int nvec = N >> 2;
    const int i = blockIdx.x * BLK + threadIdx.x;
    if (i < nvec) {
        float4 v = ((float4*)out)[i];
        v.x *= inv; v.y *= inv; v.z *= inv; v.w *= inv;
        ((float4*)out)[i] = v;
    }
    if (blockIdx.x == 0 && threadIdx.x < (N & 3))
        out[(nvec << 2) + threadIdx.x] *= inv;
}

extern "C" void kernel_launch(void* const* d_in, const int* in_sizes, int n_in,
                              void* d_out, int out_size, void* d_ws, size_t ws_size,
                              hipStream_t stream) {
    const float* mu_raw   = (const float*)d_in[0];
    const float* Dmu_raw  = (const float*)d_in[1];
    const float* T0mu_raw = (const float*)d_in[2];
    const float* Ly_raw   = (const float*)d_in[3];
    const float* xo_raw   = (const float*)d_in[4];
    const float* yo_raw   = (const float*)d_in[5];
    float* out = (float*)d_out;
    const int N = out_size;
    int nb = (N + BLK - 1) / BLK;
    const int nb_setup = (NMODES + BLK - 1) / BLK;
    if (nb < nb_setup) nb = nb_setup;
    const int nbv = ((N >> 2) + BLK - 1) / BLK > 0 ? ((N >> 2) + BLK - 1) / BLK : 1;

    setup_zero_kernel<<<nb, BLK, 0, stream>>>(mu_raw, Dmu_raw, T0mu_raw,
                                              Ly_raw, xo_raw, yo_raw, out, N);
    modal_main_kernel<<<dim3((N + BLK - 1) / BLK, G), BLK, 0, stream>>>(out, N);
    block_max_kernel<<<nbv, BLK, 0, stream>>>(out, N);
    scale_kernel<<<nbv, BLK, 0, stream>>>(out, N);
}

// Round 4
// 92.355 us; speedup vs baseline: 1.2545x; 1.0410x over previous
//
#include <hip/hip_runtime.h>
#include <math.h>

#define BLK 256
#define G 32
#define NMODES 6400
#define STRIPE (NMODES / G)   /* 200 */
#define MDIM 80
#define TILE 1024             /* samples per block (x) */
#define SPT 4                 /* samples per thread = TILE/BLK */

// Persistent device-global mode tables (rewritten every call).
__device__ float4   g_rec1[NMODES];   // {w_rev_hi, w_rev_lo, z=-sig*K*log2e, A}
__device__ float4   g_rec2[NMODES];   // {cos(2pi*256w), sin(2pi*256w), 2^(256z), 0}
__device__ unsigned g_maxbits;

// Raw gfx950 transcendentals. v_sin/v_cos input is REVOLUTIONS (sin(x*2pi)),
// pre-reduced with v_fract. v_exp_f32: D = 2^S0.
__device__ __forceinline__ float v_fract(float x){ float r; asm("v_fract_f32 %0, %1" : "=v"(r) : "v"(x)); return r; }
__device__ __forceinline__ float v_sin_rev(float x){ float r; asm("v_sin_f32 %0, %1" : "=v"(r) : "v"(x)); return r; }
__device__ __forceinline__ float v_cos_rev(float x){ float r; asm("v_cos_f32 %0, %1" : "=v"(r) : "v"(x)); return r; }
__device__ __forceinline__ float v_exp2(float x){ float r; asm("v_exp_f32 %0, %1" : "=v"(r) : "v"(x)); return r; }

__device__ __forceinline__ double softplus_d(double x) {
    return (x > 30.0) ? x : log1p(exp(x));
}

// Dispatch 1: derive all 6400 mode records once (f64), reset max slot.
__global__ __launch_bounds__(BLK) void setup_kernel(
    const float* __restrict__ mu_raw_p, const float* __restrict__ Dmu_raw_p,
    const float* __restrict__ T0mu_raw_p, const float* __restrict__ Ly_raw_p,
    const float* __restrict__ xo_raw_p, const float* __restrict__ yo_raw_p)
{
    const int gid = blockIdx.x * BLK + threadIdx.x;
    if (gid == 0) g_maxbits = 0u;
    if (gid >= NMODES) return;

    const double PI_D     = 3.14159265358979323846;
    const double TWO_PI_D = 6.28318530717958647693;
    const double INV2PI_D = 0.15915494309189533577;
    const double LOG2E_D  = 1.44269504088896340736;
    const double LX = 0.5;
    const double Kd = 1.0 / 44100.0;
    const double MAX_OM = 10000.0 * TWO_PI_D;
    const double MIN_OM = 20.0 * TWO_PI_D;

    // float32-rounded constants, exactly as the reference bakes them
    const double OM2   = TWO_PI_D * 500.0;
    const double DOMSQ = OM2 * OM2;
    const float ALPHA_F = (float)(3.0 * log(10.0) / DOMSQ * (OM2 * OM2 / 6.0));
    const float BETA_F  = (float)(3.0 * log(10.0) / DOMSQ * (1.0 / 1.0 - 1.0 / 6.0));

    const double mu   = softplus_d((double)mu_raw_p[0])  + 1e-4;
    const double Dmu  = softplus_d((double)Dmu_raw_p[0]) + 1e-4;
    const double T0mu = softplus_d((double)T0mu_raw_p[0]) + 1e-4;
    const double Ly   = 1.1 + (4.0 - 1.1) * ((tanh((double)Ly_raw_p[0]) + 1.0) * 0.5);
    const double xo   = 0.49 * LX + (1.0 - 0.49) * LX * ((tanh((double)xo_raw_p[0]) + 1.0) * 0.5);
    const double yo   = 0.51 * Ly + (1.0 - 0.51) * Ly * ((tanh((double)yo_raw_p[0]) + 1.0) * 0.5);
    const double xi = 0.1 * LX;
    const double yi = 0.1 * Ly;
    const double ms = 0.25 * mu * LX * Ly;

    const double mm = (double)(gid / MDIM + 1);   // M_VEC
    const double nn = (double)(gid % MDIM + 1);   // N_VEC
    const double a1 = mm * PI_D / LX;
    const double a2 = nn * PI_D / Ly;
    const double g1 = a1 * a1 + a2 * a2;
    double osq = T0mu * g1 + Dmu * g1 * g1;
    if (osq < 0.0) osq = 0.0;
    const double omega = sqrt(osq);

    float4 r1 = make_float4(0.0f, 0.0f, 0.0f, 0.0f);
    float4 r2 = make_float4(1.0f, 0.0f, 1.0f, 0.0f);
    if (omega >= MIN_OM && omega <= MAX_OM) {
        const double w     = omega * Kd;
        const double sig   = (double)ALPHA_F + (double)BETA_F * (omega * omega);
        const double in_w  = cos(xi * a1) * cos(yi * a2);
        const double out_w = cos(xo * a1) * cos(yo * a2);
        const double denom = sin(w) + 1e-8;
        // term_n = A * exp(-sig*K*n) * sin(n*w)
        const double A = out_w * in_w * (Kd * Kd) / ms / denom;
        const double wrev = w * INV2PI_D;
        const float hi = (float)wrev;
        const float lo = (float)(wrev - (double)hi);
        const double z = -sig * Kd * LOG2E_D;            // log2 decay per sample
        // Delta = 256-sample step constants for the in-thread recurrence
        const double dph = 256.0 * w;                    // radians
        r1 = make_float4(hi, lo, (float)z, (float)A);
        r2 = make_float4((float)cos(dph), (float)sin(dph),
                         (float)exp2(256.0 * z), 0.0f);
    }
    g_rec1[gid] = r1;
    g_rec2[gid] = r2;
}

// Dispatch 2: grid (ceil(N/1024), G). Block (bx,gy) computes samples
// [bx*1024, bx*1024+1024) over mode stripe {gy + G*j}; thread t covers
// samples t, t+256, t+512, t+768 via sin/cos rotation + exp recurrence.
// Writes a private partial row in d_ws — no atomics anywhere.
__global__ __launch_bounds__(BLK) void modal_main_kernel(
    float* __restrict__ partial, int pstride)
{
    __shared__ float4 md1[STRIPE];
    __shared__ float4 md2[STRIPE];
    __shared__ int cnt;
    if (threadIdx.x == 0) cnt = 0;
    __syncthreads();

    const int n0  = blockIdx.x * TILE;
    const int gy  = blockIdx.y;
    const float n0f = (float)n0;
    const int lane = threadIdx.x & 63;

    {   // STRIPE (200) <= BLK: single compaction pass, wave-aggregated
        const int j = threadIdx.x;
        bool alive = false;
        float4 o1, o2;
        if (j < STRIPE) {
            const float4 rec = g_rec1[gy + G * j];
            if (rec.w != 0.0f) {
                const float amp0 = rec.w * v_exp2(rec.z * n0f);  // decay to tile base
                if (fabsf(amp0) >= 1e-20f) {
                    const double wrev = (double)rec.x + (double)rec.y;
                    const double p0   = (double)n0 * wrev;
                    const float base  = (float)(p0 - rint(p0));  // phase base (revs)
                    o1 = make_float4(base, rec.x, rec.z, amp0);
                    o2 = g_rec2[gy + G * j];
                    alive = true;
                }
            }
        }
        const unsigned long long mask = __ballot(alive);
        const int nw = __popcll(mask);
        int base_slot = 0;
        if (lane == 0 && nw) base_slot = atomicAdd(&cnt, nw);
        base_slot = __shfl(base_slot, 0, 64);
        if (alive) {
            const int s = base_slot + __popcll(mask & ((1ull << lane) - 1ull));
            md1[s] = o1;
            md2[s] = o2;
        }
    }
    __syncthreads();

    const int count = cnt;
    const float tf = (float)threadIdx.x;
    float acc0 = 0.0f, acc1 = 0.0f, acc2 = 0.0f, acc3 = 0.0f;
    for (int j = 0; j < count; ++j) {
        const float4 v1 = md1[j];                // broadcast LDS reads
        const float4 v2 = md2[j];
        const float rev = v_fract(fmaf(tf, v1.y, v1.x));
        float s = v_sin_rev(rev);
        float c = v_cos_rev(rev);
        float amp = v1.w * v_exp2(v1.z * tf);
        acc0 = fmaf(amp, s, acc0);
        // rotate phase by +256 samples, decay amp by eD; 3 more samples
        const float cD = v2.x, sD = v2.y, eD = v2.z;
        float s1 = fmaf(s, cD,  c * sD);
        float c1 = fmaf(c, cD, -s * sD);
        amp *= eD;
        acc1 = fmaf(amp, s1, acc1);
        float s2 = fmaf(s1, cD,  c1 * sD);
        float c2 = fmaf(c1, cD, -s1 * sD);
        amp *= eD;
        acc2 = fmaf(amp, s2, acc2);
        float s3 = fmaf(s2, cD,  c2 * sD);
        amp *= eD;
        acc3 = fmaf(amp, s3, acc3);
        (void)c2; (void)s3;
    }
    // Unconditional stores into this block's private slice of row gy
    // (pstride is a multiple of TILE, so no overflow; rows fully rewritten
    // every call, so the 0xAA ws poison is never read).
    float* row = partial + (size_t)gy * pstride + n0 + threadIdx.x;
    row[0]   = acc0;
    row[256] = acc1;
    row[512] = acc2;
    row[768] = acc3;
}

// Dispatch 3: out[n] = sum_g partial[g][n]; block max -> atomicMax.
__global__ __launch_bounds__(BLK) void combine_max_kernel(
    const float* __restrict__ partial, int pstride,
    float* __restrict__ out, int N)
{
    const int nvec = N >> 2;
    const int i = blockIdx.x * BLK + threadIdx.x;
    float m = 0.0f;
    if (i < nvec) {
        float4 s = make_float4(0.0f, 0.0f, 0.0f, 0.0f);
        const float4* p4 = (const float4*)partial;
        const int vstride = pstride >> 2;
        #pragma unroll
        for (int g = 0; g < G; ++g) {
            const float4 v = p4[(size_t)g * vstride + i];
            s.x += v.x; s.y += v.y; s.z += v.z; s.w += v.w;
        }
        ((float4*)out)[i] = s;
        m = fmaxf(fmaxf(fabsf(s.x), fabsf(s.y)), fmaxf(fabsf(s.z), fabsf(s.w)));
    }
    if (blockIdx.x == 0 && threadIdx.x < (N & 3)) {        // scalar tail
        const int n = (nvec << 2) + threadIdx.x;
        float sv = 0.0f;
        for (int g = 0; g < G; ++g) sv += partial[(size_t)g * pstride + n];
        out[n] = sv;
        m = fmaxf(m, fabsf(sv));
    }
    #pragma unroll
    for (int o = 32; o > 0; o >>= 1) m = fmaxf(m, __shfl_down(m, o));
    __shared__ float sm[4];
    const int w = threadIdx.x >> 6, l = threadIdx.x & 63;
    if (l == 0) sm[w] = m;
    __syncthreads();
    if (threadIdx.x == 0) {
        const float mm = fmaxf(fmaxf(sm[0], sm[1]), fmaxf(sm[2], sm[3]));
        atomicMax(&g_maxbits, __float_as_uint(mm));
    }
}

// Dispatch 4: normalize.
__global__ __launch_bounds__(BLK) void scale_kernel(float* __restrict__ out, int N)
{
    const float inv = 1.0f / (__uint_as_float(g_maxbits) + 1e-8f);
    const int nvec = N >> 2;
    const int i = blockIdx.x * BLK + threadIdx.x;
    if (i < nvec) {
        float4 v = ((float4*)out)[i];
        v.x *= inv; v.y *= inv; v.z *= inv; v.w *= inv;
        ((float4*)out)[i] = v;
    }
    if (blockIdx.x == 0 && threadIdx.x < (N & 3))
        out[(nvec << 2) + threadIdx.x] *= inv;
}

extern "C" void kernel_launch(void* const* d_in, const int* in_sizes, int n_in,
                              void* d_out, int out_size, void* d_ws, size_t ws_size,
                              hipStream_t stream) {
    const float* mu_raw   = (const float*)d_in[0];
    const float* Dmu_raw  = (const float*)d_in[1];
    const float* T0mu_raw = (const float*)d_in[2];
    const float* Ly_raw   = (const float*)d_in[3];
    const float* xo_raw   = (const float*)d_in[4];
    const float* yo_raw   = (const float*)d_in[5];
    float* out = (float*)d_out;
    float* partial = (float*)d_ws;       // G rows x pstride floats (~5.8 MB)
    const int N = out_size;

    const int ntiles  = (N + TILE - 1) / TILE;
    const int pstride = ntiles * TILE;
    const int nb_setup = (NMODES + BLK - 1) / BLK;
    int nbv = ((N >> 2) + BLK - 1) / BLK;
    if (nbv < 1) nbv = 1;

    setup_kernel<<<nb_setup, BLK, 0, stream>>>(mu_raw, Dmu_raw, T0mu_raw,
                                               Ly_raw, xo_raw, yo_raw);
    modal_main_kernel<<<dim3(ntiles, G), BLK, 0, stream>>>(partial, pstride);
    combine_max_kernel<<<nbv, BLK, 0, stream>>>(partial, pstride, out, N);
    scale_kernel<<<nbv, BLK, 0, stream>>>(out, N);
}